// Round 7
// baseline (69.282 us; speedup 1.0000x reference)
//
#include <hip/hip_runtime.h>
#include <math.h>

#define DIM 128
#define PSTRIDE 132          // per-partial floats: m, l, pad2, acc[128] (16B-aligned acc)
#define NEG_BIG (-3.0e38f)

// ---------------------------------------------------------------------------
// Fused single pass. 4 lanes per row ("quad"), 16 rows per wave-chunk.
// Per chunk: lane loads its 32 key cols (8x float4) + 32 value cols, computes
// its row's L1 partial, 2 shfl_xor fold the quad -> EVERY lane holds its row's
// full logit. Per-lane online softmax (m, l, acc[8]x4) over the lane's private
// row stream -- no cross-lane carried state in the loop. End: lanes merge via
// the associative (m,l,acc) rule. One partial (m, l, acc[128]) per wave.
// P=8192 waves -> 32 waves/CU (full occupancy): latency hidden by TLP.
// ---------------------------------------------------------------------------
__global__ __launch_bounds__(256) void nd_fused(const float* __restrict__ query,
                                                const float* __restrict__ keys,
                                                const float* __restrict__ values,
                                                float* __restrict__ part,
                                                int nrows, int nchunks, int P) {
    const int tid  = threadIdx.x;
    const int lane = tid & 63;
    const int quad = lane & 3;
    const int rsub = lane >> 2;                       // 0..15
    const int wid  = blockIdx.x * (blockDim.x >> 6) + (tid >> 6);

    float4 qv[8];
    #pragma unroll
    for (int j = 0; j < 8; ++j)
        qv[j] = *reinterpret_cast<const float4*>(query + quad * 4 + j * 16);

    float  m = NEG_BIG;
    float  l = 0.f;
    float4 acc[8];
    #pragma unroll
    for (int j = 0; j < 8; ++j) acc[j] = make_float4(0.f, 0.f, 0.f, 0.f);

    for (int c = wid; c < nchunks; c += P) {
        const int  row = c * 16 + rsub;
        const bool ok  = row < nrows;
        const int  rr  = ok ? row : (nrows - 1);
        const float* kp = keys   + (size_t)rr * DIM + quad * 4;
        const float* vp = values + (size_t)rr * DIM + quad * 4;

        float4 kv[8], vv[8];
        #pragma unroll
        for (int j = 0; j < 8; ++j)
            kv[j] = *reinterpret_cast<const float4*>(kp + j * 16);
        #pragma unroll
        for (int j = 0; j < 8; ++j)
            vv[j] = *reinterpret_cast<const float4*>(vp + j * 16);

        float s = 0.f;
        #pragma unroll
        for (int j = 0; j < 8; ++j)
            s += fabsf(kv[j].x - qv[j].x) + fabsf(kv[j].y - qv[j].y)
               + fabsf(kv[j].z - qv[j].z) + fabsf(kv[j].w - qv[j].w);
        s += __shfl_xor(s, 1, 64);                    // fold quad: all 4 lanes
        s += __shfl_xor(s, 2, 64);                    // now hold the full logit
        const float lg = ok ? -s : NEG_BIG;

        const float newm  = fmaxf(m, lg);
        const float scale = __expf(m - newm);         // 0 on first valid chunk
        const float w     = ok ? __expf(lg - newm) : 0.f;
        l = l * scale + w;
        #pragma unroll
        for (int j = 0; j < 8; ++j) {
            acc[j].x = acc[j].x * scale + w * vv[j].x;
            acc[j].y = acc[j].y * scale + w * vv[j].y;
            acc[j].z = acc[j].z * scale + w * vv[j].z;
            acc[j].w = acc[j].w * scale + w * vv[j].w;
        }
        m = newm;
    }

    // Wave max: m is quad-uniform, so reduce over rsub only (offs 4..32).
    float M = m;
    #pragma unroll
    for (int off = 4; off < 64; off <<= 1)
        M = fmaxf(M, __shfl_xor(M, off, 64));
    const float e = __expf(m - M);                    // m==NEG_BIG -> 0
    l *= e;
    #pragma unroll
    for (int j = 0; j < 8; ++j) {
        acc[j].x *= e; acc[j].y *= e; acc[j].z *= e; acc[j].w *= e;
    }

    // Sum over rsub (quad fixed): cols summed over the 16 row-streams.
    #pragma unroll
    for (int off = 4; off < 64; off <<= 1) {
        #pragma unroll
        for (int j = 0; j < 8; ++j) {
            acc[j].x += __shfl_xor(acc[j].x, off, 64);
            acc[j].y += __shfl_xor(acc[j].y, off, 64);
            acc[j].z += __shfl_xor(acc[j].z, off, 64);
            acc[j].w += __shfl_xor(acc[j].w, off, 64);
        }
        l += __shfl_xor(l, off, 64);   // each row counted once per quad lane
    }

    if (rsub == 0) {                   // lanes 0..3 hold the wave's 128-col partial
        float* wp = part + (size_t)wid * PSTRIDE;
        if (quad == 0) { wp[0] = M; wp[1] = l; }
        #pragma unroll
        for (int j = 0; j < 8; ++j)
            *reinterpret_cast<float4*>(wp + 4 + quad * 4 + j * 16) = acc[j];
    }
}

// ---------------------------------------------------------------------------
// Merge 64 consecutive partials into one with the max-aware rule:
//   M = max m_p; e_p = exp(m_p - M); l = sum l_p e_p; acc[d] = sum acc_p[d] e_p
// ---------------------------------------------------------------------------
__global__ __launch_bounds__(256) void nd_merge(const float* __restrict__ part,
                                                float* __restrict__ part2) {
    __shared__ float sh_e[64];
    __shared__ float sh_red[256];
    __shared__ float shM, shL;
    const int tid  = threadIdx.x;
    const int base = blockIdx.x * 64;

    if (tid < 64) {
        const float mm = part[(size_t)(base + tid) * PSTRIDE];
        float r = mm;
        #pragma unroll
        for (int off = 32; off > 0; off >>= 1)
            r = fmaxf(r, __shfl_xor(r, off, 64));
        const float e = __expf(mm - r);
        sh_e[tid] = e;
        float lp = part[(size_t)(base + tid) * PSTRIDE + 1] * e;
        #pragma unroll
        for (int off = 32; off > 0; off >>= 1)
            lp += __shfl_xor(lp, off, 64);
        if (tid == 0) { shM = r; shL = lp; }
    }
    __syncthreads();

    const int d = tid & 127, g = tid >> 7;
    float o = 0.f;
    for (int p = g; p < 64; p += 2)
        o += part[(size_t)(base + p) * PSTRIDE + 4 + d] * sh_e[p];
    sh_red[tid] = o;
    __syncthreads();

    if (tid < 128) {
        float* wp = part2 + (size_t)blockIdx.x * PSTRIDE;
        if (tid == 0) { wp[0] = shM; wp[1] = shL; }
        wp[4 + tid] = sh_red[tid] + sh_red[tid + 128];
    }
}

// ---------------------------------------------------------------------------
// Final: merge the B2 (<=128) level-2 partials, normalize, write out[128].
// ---------------------------------------------------------------------------
__global__ __launch_bounds__(256) void nd_final(const float* __restrict__ part2,
                                                float* __restrict__ out, int B2) {
    __shared__ float sh_e[128];
    __shared__ float sh_red[256];
    __shared__ float shL;
    const int tid = threadIdx.x;

    if (tid < 64) {
        const float m0 = (tid      < B2) ? part2[(size_t)tid * PSTRIDE]        : NEG_BIG;
        const float m1 = (tid + 64 < B2) ? part2[(size_t)(tid + 64) * PSTRIDE] : NEG_BIG;
        float r = fmaxf(m0, m1);
        #pragma unroll
        for (int off = 32; off > 0; off >>= 1)
            r = fmaxf(r, __shfl_xor(r, off, 64));
        const float e0 = (tid      < B2) ? __expf(m0 - r) : 0.f;
        const float e1 = (tid + 64 < B2) ? __expf(m1 - r) : 0.f;
        sh_e[tid] = e0; sh_e[tid + 64] = e1;
        float lp = 0.f;
        if (tid      < B2) lp += part2[(size_t)tid * PSTRIDE + 1] * e0;
        if (tid + 64 < B2) lp += part2[(size_t)(tid + 64) * PSTRIDE + 1] * e1;
        #pragma unroll
        for (int off = 32; off > 0; off >>= 1)
            lp += __shfl_xor(lp, off, 64);
        if (tid == 0) shL = lp;
    }
    __syncthreads();

    const int d = tid & 127, g = tid >> 7;
    float o = 0.f;
    for (int p = g; p < B2; p += 2)
        o += part2[(size_t)p * PSTRIDE + 4 + d] * sh_e[p];
    sh_red[tid] = o;
    __syncthreads();

    if (tid < 128)
        out[tid] = (sh_red[tid] + sh_red[tid + 128]) / shL;
}

extern "C" void kernel_launch(void* const* d_in, const int* in_sizes, int n_in,
                              void* d_out, int out_size, void* d_ws, size_t ws_size,
                              hipStream_t stream) {
    const float* query  = (const float*)d_in[0];
    const float* keys   = (const float*)d_in[1];
    const float* values = (const float*)d_in[2];
    float* out = (float*)d_out;
    float* ws  = (float*)d_ws;

    const int nrows   = in_sizes[1] / DIM;
    const int nchunks = (nrows + 15) / 16;

    int P = 8192;                                    // waves: 32/CU -> full occupancy
    const size_t capf = ws_size / sizeof(float);
    while ((size_t)(P + P / 64) * PSTRIDE > capf && P > 512) P >>= 1;
    const int B2 = P / 64;

    float* part  = ws;
    float* part2 = part + (size_t)P * PSTRIDE;

    nd_fused<<<P / 4, 256, 0, stream>>>(query, keys, values, part, nrows, nchunks, P);
    nd_merge<<<B2,    256, 0, stream>>>(part, part2);
    nd_final<<<1,     256, 0, stream>>>(part2, out, B2);
}

// Round 8
// 51.824 us; speedup vs baseline: 1.3369x; 1.3369x over previous
//
#include <hip/hip_runtime.h>
#include <math.h>

#define DIM 128
#define PSTRIDE 132          // per-partial floats: m, l, pad2, acc[128] (16B-aligned acc)
#define NEG_BIG (-3.0e38f)

// ---------------------------------------------------------------------------
// Fused single pass, 2-slot software pipeline.
// Quad layout: 4 lanes per row, 16 rows per wave-chunk; lane holds 32 cols
// (8x float4). Per iteration the wave processes TWO independent chunks
// (c and c+P) with fully separate online-softmax state (m,l,acc[8]) each:
// the two chains interleave, 32 float4 loads issue per iteration.
// __launch_bounds__(256,2) -> VGPR cap 256 so loads stay in flight.
// Slots merge at wave end (associative rule), then lanes merge over rsub.
// ---------------------------------------------------------------------------
__global__ __launch_bounds__(256, 2) void nd_fused(const float* __restrict__ query,
                                                   const float* __restrict__ keys,
                                                   const float* __restrict__ values,
                                                   float* __restrict__ part,
                                                   int nrows, int nchunks, int P) {
    const int tid  = threadIdx.x;
    const int lane = tid & 63;
    const int quad = lane & 3;
    const int rsub = lane >> 2;                       // 0..15
    const int wid  = blockIdx.x * (blockDim.x >> 6) + (tid >> 6);

    float4 qv[8];
    #pragma unroll
    for (int j = 0; j < 8; ++j)
        qv[j] = *reinterpret_cast<const float4*>(query + quad * 4 + j * 16);

    float  m0 = NEG_BIG, l0 = 0.f;
    float  m1 = NEG_BIG, l1 = 0.f;
    float4 acc0[8], acc1[8];
    #pragma unroll
    for (int j = 0; j < 8; ++j) {
        acc0[j] = make_float4(0.f, 0.f, 0.f, 0.f);
        acc1[j] = make_float4(0.f, 0.f, 0.f, 0.f);
    }

    int c = wid;
    for (; c + P < nchunks; c += 2 * P) {
        const int  rowA = c * 16 + rsub;
        const int  rowB = (c + P) * 16 + rsub;
        const bool okA  = rowA < nrows;
        const bool okB  = rowB < nrows;
        const int  rA   = okA ? rowA : (nrows - 1);
        const int  rB   = okB ? rowB : (nrows - 1);
        const float* kpA = keys   + (size_t)rA * DIM + quad * 4;
        const float* kpB = keys   + (size_t)rB * DIM + quad * 4;
        const float* vpA = values + (size_t)rA * DIM + quad * 4;
        const float* vpB = values + (size_t)rB * DIM + quad * 4;

        float4 kvA[8], kvB[8], vvA[8], vvB[8];
        #pragma unroll
        for (int j = 0; j < 8; ++j) kvA[j] = *reinterpret_cast<const float4*>(kpA + j * 16);
        #pragma unroll
        for (int j = 0; j < 8; ++j) kvB[j] = *reinterpret_cast<const float4*>(kpB + j * 16);
        #pragma unroll
        for (int j = 0; j < 8; ++j) vvA[j] = *reinterpret_cast<const float4*>(vpA + j * 16);
        #pragma unroll
        for (int j = 0; j < 8; ++j) vvB[j] = *reinterpret_cast<const float4*>(vpB + j * 16);

        float sA = 0.f, sB = 0.f;
        #pragma unroll
        for (int j = 0; j < 8; ++j) {
            sA += fabsf(kvA[j].x - qv[j].x) + fabsf(kvA[j].y - qv[j].y)
                + fabsf(kvA[j].z - qv[j].z) + fabsf(kvA[j].w - qv[j].w);
            sB += fabsf(kvB[j].x - qv[j].x) + fabsf(kvB[j].y - qv[j].y)
                + fabsf(kvB[j].z - qv[j].z) + fabsf(kvB[j].w - qv[j].w);
        }
        sA += __shfl_xor(sA, 1, 64);  sB += __shfl_xor(sB, 1, 64);
        sA += __shfl_xor(sA, 2, 64);  sB += __shfl_xor(sB, 2, 64);
        const float lgA = okA ? -sA : NEG_BIG;
        const float lgB = okB ? -sB : NEG_BIG;

        const float nmA = fmaxf(m0, lgA);
        const float nmB = fmaxf(m1, lgB);
        const float scA = __expf(m0 - nmA);
        const float scB = __expf(m1 - nmB);
        const float wA  = okA ? __expf(lgA - nmA) : 0.f;
        const float wB  = okB ? __expf(lgB - nmB) : 0.f;
        l0 = l0 * scA + wA;
        l1 = l1 * scB + wB;
        #pragma unroll
        for (int j = 0; j < 8; ++j) {
            acc0[j].x = acc0[j].x * scA + wA * vvA[j].x;
            acc0[j].y = acc0[j].y * scA + wA * vvA[j].y;
            acc0[j].z = acc0[j].z * scA + wA * vvA[j].z;
            acc0[j].w = acc0[j].w * scA + wA * vvA[j].w;
            acc1[j].x = acc1[j].x * scB + wB * vvB[j].x;
            acc1[j].y = acc1[j].y * scB + wB * vvB[j].y;
            acc1[j].z = acc1[j].z * scB + wB * vvB[j].z;
            acc1[j].w = acc1[j].w * scB + wB * vvB[j].w;
        }
        m0 = nmA;
        m1 = nmB;
    }

    if (c < nchunks) {                                // tail chunk -> slot 0
        const int  row = c * 16 + rsub;
        const bool ok  = row < nrows;
        const int  rr  = ok ? row : (nrows - 1);
        const float* kp = keys   + (size_t)rr * DIM + quad * 4;
        const float* vp = values + (size_t)rr * DIM + quad * 4;
        float4 kv[8], vv[8];
        #pragma unroll
        for (int j = 0; j < 8; ++j) kv[j] = *reinterpret_cast<const float4*>(kp + j * 16);
        #pragma unroll
        for (int j = 0; j < 8; ++j) vv[j] = *reinterpret_cast<const float4*>(vp + j * 16);
        float s = 0.f;
        #pragma unroll
        for (int j = 0; j < 8; ++j)
            s += fabsf(kv[j].x - qv[j].x) + fabsf(kv[j].y - qv[j].y)
               + fabsf(kv[j].z - qv[j].z) + fabsf(kv[j].w - qv[j].w);
        s += __shfl_xor(s, 1, 64);
        s += __shfl_xor(s, 2, 64);
        const float lg   = ok ? -s : NEG_BIG;
        const float newm = fmaxf(m0, lg);
        const float sc   = __expf(m0 - newm);
        const float w    = ok ? __expf(lg - newm) : 0.f;
        l0 = l0 * sc + w;
        #pragma unroll
        for (int j = 0; j < 8; ++j) {
            acc0[j].x = acc0[j].x * sc + w * vv[j].x;
            acc0[j].y = acc0[j].y * sc + w * vv[j].y;
            acc0[j].z = acc0[j].z * sc + w * vv[j].z;
            acc0[j].w = acc0[j].w * sc + w * vv[j].w;
        }
        m0 = newm;
    }

    // Merge slot 1 into slot 0 (same lane, associative rule).
    {
        const float M  = fmaxf(m0, m1);
        const float e0 = __expf(m0 - M);
        const float e1 = __expf(m1 - M);
        l0 = l0 * e0 + l1 * e1;
        #pragma unroll
        for (int j = 0; j < 8; ++j) {
            acc0[j].x = acc0[j].x * e0 + acc1[j].x * e1;
            acc0[j].y = acc0[j].y * e0 + acc1[j].y * e1;
            acc0[j].z = acc0[j].z * e0 + acc1[j].z * e1;
            acc0[j].w = acc0[j].w * e0 + acc1[j].w * e1;
        }
        m0 = M;
    }

    // Wave max: m0 is quad-uniform, reduce over rsub only (offs 4..32).
    float M = m0;
    #pragma unroll
    for (int off = 4; off < 64; off <<= 1)
        M = fmaxf(M, __shfl_xor(M, off, 64));
    const float e = __expf(m0 - M);
    l0 *= e;
    #pragma unroll
    for (int j = 0; j < 8; ++j) {
        acc0[j].x *= e; acc0[j].y *= e; acc0[j].z *= e; acc0[j].w *= e;
    }

    // Sum over rsub (quad fixed): cols summed over the 16 row-streams.
    #pragma unroll
    for (int off = 4; off < 64; off <<= 1) {
        #pragma unroll
        for (int j = 0; j < 8; ++j) {
            acc0[j].x += __shfl_xor(acc0[j].x, off, 64);
            acc0[j].y += __shfl_xor(acc0[j].y, off, 64);
            acc0[j].z += __shfl_xor(acc0[j].z, off, 64);
            acc0[j].w += __shfl_xor(acc0[j].w, off, 64);
        }
        l0 += __shfl_xor(l0, off, 64);
    }

    if (rsub == 0) {                   // lanes 0..3 hold the wave's 128-col partial
        float* wp = part + (size_t)wid * PSTRIDE;
        if (quad == 0) { wp[0] = M; wp[1] = l0; }
        #pragma unroll
        for (int j = 0; j < 8; ++j)
            *reinterpret_cast<float4*>(wp + 4 + quad * 4 + j * 16) = acc0[j];
    }
}

// ---------------------------------------------------------------------------
// Merge 64 consecutive partials into one with the max-aware rule.
// ---------------------------------------------------------------------------
__global__ __launch_bounds__(256) void nd_merge(const float* __restrict__ part,
                                                float* __restrict__ part2) {
    __shared__ float sh_e[64];
    __shared__ float sh_red[256];
    __shared__ float shM, shL;
    const int tid  = threadIdx.x;
    const int base = blockIdx.x * 64;

    if (tid < 64) {
        const float mm = part[(size_t)(base + tid) * PSTRIDE];
        float r = mm;
        #pragma unroll
        for (int off = 32; off > 0; off >>= 1)
            r = fmaxf(r, __shfl_xor(r, off, 64));
        const float e = __expf(mm - r);
        sh_e[tid] = e;
        float lp = part[(size_t)(base + tid) * PSTRIDE + 1] * e;
        #pragma unroll
        for (int off = 32; off > 0; off >>= 1)
            lp += __shfl_xor(lp, off, 64);
        if (tid == 0) { shM = r; shL = lp; }
    }
    __syncthreads();

    const int d = tid & 127, g = tid >> 7;
    float o = 0.f;
    for (int p = g; p < 64; p += 2)
        o += part[(size_t)(base + p) * PSTRIDE + 4 + d] * sh_e[p];
    sh_red[tid] = o;
    __syncthreads();

    if (tid < 128) {
        float* wp = part2 + (size_t)blockIdx.x * PSTRIDE;
        if (tid == 0) { wp[0] = shM; wp[1] = shL; }
        wp[4 + tid] = sh_red[tid] + sh_red[tid + 128];
    }
}

// ---------------------------------------------------------------------------
// Final: merge the B2 (<=128) level-2 partials, normalize, write out[128].
// ---------------------------------------------------------------------------
__global__ __launch_bounds__(256) void nd_final(const float* __restrict__ part2,
                                                float* __restrict__ out, int B2) {
    __shared__ float sh_e[128];
    __shared__ float sh_red[256];
    __shared__ float shL;
    const int tid = threadIdx.x;

    if (tid < 64) {
        const float m0 = (tid      < B2) ? part2[(size_t)tid * PSTRIDE]        : NEG_BIG;
        const float m1 = (tid + 64 < B2) ? part2[(size_t)(tid + 64) * PSTRIDE] : NEG_BIG;
        float r = fmaxf(m0, m1);
        #pragma unroll
        for (int off = 32; off > 0; off >>= 1)
            r = fmaxf(r, __shfl_xor(r, off, 64));
        const float e0 = (tid      < B2) ? __expf(m0 - r) : 0.f;
        const float e1 = (tid + 64 < B2) ? __expf(m1 - r) : 0.f;
        sh_e[tid] = e0; sh_e[tid + 64] = e1;
        float lp = 0.f;
        if (tid      < B2) lp += part2[(size_t)tid * PSTRIDE + 1] * e0;
        if (tid + 64 < B2) lp += part2[(size_t)(tid + 64) * PSTRIDE + 1] * e1;
        #pragma unroll
        for (int off = 32; off > 0; off >>= 1)
            lp += __shfl_xor(lp, off, 64);
        if (tid == 0) shL = lp;
    }
    __syncthreads();

    const int d = tid & 127, g = tid >> 7;
    float o = 0.f;
    for (int p = g; p < B2; p += 2)
        o += part2[(size_t)p * PSTRIDE + 4 + d] * sh_e[p];
    sh_red[tid] = o;
    __syncthreads();

    if (tid < 128)
        out[tid] = (sh_red[tid] + sh_red[tid + 128]) / shL;
}

extern "C" void kernel_launch(void* const* d_in, const int* in_sizes, int n_in,
                              void* d_out, int out_size, void* d_ws, size_t ws_size,
                              hipStream_t stream) {
    const float* query  = (const float*)d_in[0];
    const float* keys   = (const float*)d_in[1];
    const float* values = (const float*)d_in[2];
    float* out = (float*)d_out;
    float* ws  = (float*)d_ws;

    const int nrows   = in_sizes[1] / DIM;
    const int nchunks = (nrows + 15) / 16;

    int P = 2048;                                    // waves (512 blocks, 2 blocks/CU)
    const size_t capf = ws_size / sizeof(float);
    while ((size_t)(P + P / 64) * PSTRIDE > capf && P > 512) P >>= 1;
    const int B2 = P / 64;

    float* part  = ws;
    float* part2 = part + (size_t)P * PSTRIDE;

    nd_fused<<<P / 4, 256, 0, stream>>>(query, keys, values, part, nrows, nchunks, P);
    nd_merge<<<B2,    256, 0, stream>>>(part, part2);
    nd_final<<<1,     256, 0, stream>>>(part2, out, B2);
}